// Round 2
// baseline (377.512 us; speedup 1.0000x reference)
//
#include <hip/hip_runtime.h>

// BackWarp: dense bilinear backward warp, ILP/MLP-focused version.
// Evidence from rounds 0-1: HBM 36-44%, VALU 11-36%, LDS-conflict ~0, occupancy
// 61-80%, yet dur identical across two structurally different kernels =>
// latency-bound at fixed loads-in-flight. This version doubles per-thread MLP:
// each thread computes a 2x2 quad (x,x+1) x (y,y+4); all 16 corner loads issue
// before any blend (deep counted-vmcnt pipeline), flow reads are dwordx4
// (2 px per load), and adjacent-pixel outputs merge into 24B contiguous
// nontemporal stores (dwordx4 + dwordx2).

#define BW_B 16
#define BW_H 720
#define BW_W 1280
#define BW_C 3

// block 64x4 threads; thread quad = 2 x-px, 2 y-rows => tile 128 wide x 8 tall
#define TILE_W 128
#define TILE_H 8

typedef float f4u __attribute__((ext_vector_type(4), aligned(4)));
typedef float f2u __attribute__((ext_vector_type(2), aligned(4)));
typedef float f4a __attribute__((ext_vector_type(4)));   // 16B-aligned

__device__ __forceinline__ void prep(
    const float* __restrict__ imgb, float fy_flow, float fx_flow,
    int x, int y,
    const float*& p0, const float*& p1, float& ax, float& ay) {
    const float qy = (float)y - fy_flow;
    const float qx = (float)x - fx_flow;
    float fy = fminf(fmaxf(floorf(qy), 0.0f), (float)(BW_H - 2));
    float fx = fminf(fmaxf(floorf(qx), 0.0f), (float)(BW_W - 2));
    ay = fminf(fmaxf(qy - fy, 0.0f), 1.0f);
    ax = fminf(fmaxf(qx - fx, 0.0f), 1.0f);
    const int iy = (int)fy;
    const int ix = (int)fx;
    p0 = imgb + (iy * BW_W + ix) * BW_C;
    p1 = p0 + BW_W * BW_C;
}

struct Col { float c0, c1, c2; };

__device__ __forceinline__ Col blend(f4u t, f2u t2, f4u bm, f2u b2,
                                     float ax, float ay) {
    const float tl0 = t.x,  tl1 = t.y,  tl2 = t.z;
    const float tr0 = t.w,  tr1 = t2.x, tr2 = t2.y;
    const float bl0 = bm.x, bl1 = bm.y, bl2 = bm.z;
    const float br0 = bm.w, br1 = b2.x, br2 = b2.y;

    const float it0 = tl0 + ax * (tr0 - tl0);
    const float it1 = tl1 + ax * (tr1 - tl1);
    const float it2 = tl2 + ax * (tr2 - tl2);
    const float ib0 = bl0 + ax * (br0 - bl0);
    const float ib1 = bl1 + ax * (br1 - bl1);
    const float ib2 = bl2 + ax * (br2 - bl2);

    Col r;
    r.c0 = it0 + ay * (ib0 - it0);
    r.c1 = it1 + ay * (ib1 - it1);
    r.c2 = it2 + ay * (ib2 - it2);
    return r;
}

__global__ __launch_bounds__(256) void backwarp_kernel(
    const float* __restrict__ image,
    const float* __restrict__ flow,
    float* __restrict__ out) {
    const int tx = threadIdx.x;                    // 0..63
    const int ty = threadIdx.y;                    // 0..3
    const int x = blockIdx.x * TILE_W + tx * 2;    // even x; quad covers x, x+1
    const int ya = blockIdx.y * TILE_H + ty;       // rows ty and ty+4
    const int yb = ya + 4;
    const int b = blockIdx.z;

    const float* __restrict__ imgb = image + (size_t)b * (BW_H * BW_W * BW_C);
    const unsigned base_b = (unsigned)b * (BW_H * BW_W);
    const unsigned iA = base_b + (unsigned)ya * BW_W + (unsigned)x;  // even
    const unsigned iB = base_b + (unsigned)yb * BW_W + (unsigned)x;  // even

    // flow for both x-px of a row in one 16B load (read-once stream -> NT)
    const f4a* __restrict__ fl = (const f4a*)flow;
    const f4a fA = __builtin_nontemporal_load(fl + (iA >> 1));  // px A0, A1
    const f4a fB = __builtin_nontemporal_load(fl + (iB >> 1));  // px B0, B1

    // ---- address prep for 4 pixels ----
    const float *pA0t, *pA0b, *pA1t, *pA1b, *pB0t, *pB0b, *pB1t, *pB1b;
    float axA0, ayA0, axA1, ayA1, axB0, ayB0, axB1, ayB1;
    prep(imgb, fA.x, fA.y, x,     ya, pA0t, pA0b, axA0, ayA0);
    prep(imgb, fA.z, fA.w, x + 1, ya, pA1t, pA1b, axA1, ayA1);
    prep(imgb, fB.x, fB.y, x,     yb, pB0t, pB0b, axB0, ayB0);
    prep(imgb, fB.z, fB.w, x + 1, yb, pB1t, pB1b, axB1, ayB1);

    // ---- issue all 16 corner loads (deep vmcnt pipeline) ----
    const f4u tA0  = *(const f4u*)pA0t;  const f2u tA0b = *(const f2u*)(pA0t + 4);
    const f4u bA0  = *(const f4u*)pA0b;  const f2u bA0b = *(const f2u*)(pA0b + 4);
    const f4u tA1  = *(const f4u*)pA1t;  const f2u tA1b = *(const f2u*)(pA1t + 4);
    const f4u bA1  = *(const f4u*)pA1b;  const f2u bA1b = *(const f2u*)(pA1b + 4);
    const f4u tB0  = *(const f4u*)pB0t;  const f2u tB0b = *(const f2u*)(pB0t + 4);
    const f4u bB0  = *(const f4u*)pB0b;  const f2u bB0b = *(const f2u*)(pB0b + 4);
    const f4u tB1  = *(const f4u*)pB1t;  const f2u tB1b = *(const f2u*)(pB1t + 4);
    const f4u bB1  = *(const f4u*)pB1b;  const f2u bB1b = *(const f2u*)(pB1b + 4);

    // ---- blend + merged 24B stores per row ----
    const Col rA0 = blend(tA0, tA0b, bA0, bA0b, axA0, ayA0);
    const Col rA1 = blend(tA1, tA1b, bA1, bA1b, axA1, ayA1);
    {
        float* o = out + (size_t)iA * BW_C;   // byte addr = 12*iA, iA even => 8B+
        const f4u s0 = {rA0.c0, rA0.c1, rA0.c2, rA1.c0};
        const f2u s1 = {rA1.c1, rA1.c2};
        __builtin_nontemporal_store(s0, (f4u*)o);
        __builtin_nontemporal_store(s1, (f2u*)(o + 4));
    }

    const Col rB0 = blend(tB0, tB0b, bB0, bB0b, axB0, ayB0);
    const Col rB1 = blend(tB1, tB1b, bB1, bB1b, axB1, ayB1);
    {
        float* o = out + (size_t)iB * BW_C;
        const f4u s0 = {rB0.c0, rB0.c1, rB0.c2, rB1.c0};
        const f2u s1 = {rB1.c1, rB1.c2};
        __builtin_nontemporal_store(s0, (f4u*)o);
        __builtin_nontemporal_store(s1, (f2u*)(o + 4));
    }
}

extern "C" void kernel_launch(void* const* d_in, const int* in_sizes, int n_in,
                              void* d_out, int out_size, void* d_ws, size_t ws_size,
                              hipStream_t stream) {
    const float* image = (const float*)d_in[0];
    const float* flow  = (const float*)d_in[1];
    float* out = (float*)d_out;

    dim3 block(64, 4, 1);                                   // 256 threads
    dim3 grid(BW_W / TILE_W, BW_H / TILE_H, BW_B);          // 10 x 90 x 16
    backwarp_kernel<<<grid, block, 0, stream>>>(image, flow, out);
}

// Round 3
// 370.707 us; speedup vs baseline: 1.0184x; 1.0184x over previous
//
#include <hip/hip_runtime.h>

// BackWarp: dense bilinear backward warp.
// Round-3 theory: rounds 0-2 (divergent-gather / LDS-staged / 2x-MLP) all hit
// ~137 us with VALU<36%, HBM<45%, occupancy 60-80% => shared external wall.
// Candidate: cross-XCD L2 duplication. Default dispatch round-robins consecutive
// blocks over 8 XCDs, so all 8 private L2s fill the SAME image y-band: ~8x177MB
// = 1.4GB of L3->L2 fill traffic per dispatch (~140us at ~12TB/s) - matches the
// floor. Fix: batch-affinity swizzle - XCD k (= wgid%8, measured round-robin,
// learn_hip m09) owns batches {2k, 2k+1}; image lines fill exactly one L2.
// Compute structure is byte-identical to round 0 (fastest, VGPR=20, clean
// 172.8MB write stream): 64x8 tile, 2 px/thread (rows ty, ty+4), NT stores.

#define BW_B 16
#define BW_H 720
#define BW_W 1280
#define BW_C 3

#define TILE_W 64
#define TILE_H 8

#define GRID_X (BW_W / TILE_W)   // 20
#define GRID_Y (BW_H / TILE_H)   // 90
#define WG_PER_BATCH (GRID_X * GRID_Y)          // 1800
#define NXCD 8
#define BATCH_PER_XCD (BW_B / NXCD)             // 2
#define WG_PER_XCD (WG_PER_BATCH * BATCH_PER_XCD)  // 3600

typedef float floatx2 __attribute__((ext_vector_type(2)));

__device__ __forceinline__ void warp_one(
    const float* __restrict__ imgb,  // image base for this batch
    floatx2 f, int x, int y, float* __restrict__ o) {
    const float qy = (float)y - f.x;
    const float qx = (float)x - f.y;

    float fy = floorf(qy);
    fy = fminf(fmaxf(fy, 0.0f), (float)(BW_H - 2));
    float fx = floorf(qx);
    fx = fminf(fmaxf(fx, 0.0f), (float)(BW_W - 2));
    const float ay = fminf(fmaxf(qy - fy, 0.0f), 1.0f);
    const float ax = fminf(fmaxf(qx - fx, 0.0f), 1.0f);
    const int iy = (int)fy;
    const int ix = (int)fx;

    const float* __restrict__ p0 = imgb + (iy * BW_W + ix) * BW_C;  // top-left
    const float* __restrict__ p1 = p0 + BW_W * BW_C;                // bottom-left

    const float tl0 = p0[0], tl1 = p0[1], tl2 = p0[2];
    const float tr0 = p0[3], tr1 = p0[4], tr2 = p0[5];
    const float bl0 = p1[0], bl1 = p1[1], bl2 = p1[2];
    const float br0 = p1[3], br1 = p1[4], br2 = p1[5];

    const float it0 = tl0 + ax * (tr0 - tl0);
    const float it1 = tl1 + ax * (tr1 - tl1);
    const float it2 = tl2 + ax * (tr2 - tl2);
    const float ib0 = bl0 + ax * (br0 - bl0);
    const float ib1 = bl1 + ax * (br1 - bl1);
    const float ib2 = bl2 + ax * (br2 - bl2);

    __builtin_nontemporal_store(it0 + ay * (ib0 - it0), o + 0);
    __builtin_nontemporal_store(it1 + ay * (ib1 - it1), o + 1);
    __builtin_nontemporal_store(it2 + ay * (ib2 - it2), o + 2);
}

__global__ __launch_bounds__(256) void backwarp_kernel(
    const float* __restrict__ image,
    const float* __restrict__ flow,
    float* __restrict__ out) {
    // ---- batch-affinity XCD swizzle ----
    // HW round-robins consecutive wgids over 8 XCDs; give XCD k a contiguous
    // work queue covering exactly batches {2k, 2k+1}, x-major then y then b.
    const unsigned wg = blockIdx.x;          // 0..28799
    const unsigned xcd = wg & (NXCD - 1);    // 0..7
    const unsigned w = wg >> 3;              // 0..3599 within this XCD
    const unsigned b = xcd * BATCH_PER_XCD + w / WG_PER_BATCH;
    const unsigned rem = w % WG_PER_BATCH;   // 0..1799
    const unsigned by = rem / GRID_X;        // 0..89
    const unsigned bx = rem % GRID_X;        // 0..19

    const int x = (int)(bx * TILE_W + threadIdx.x);      // [0, W)
    const int y0 = (int)(by * TILE_H + threadIdx.y);     // rows ty and ty+4
    const int y1 = y0 + 4;

    const float* __restrict__ imgb = image + (size_t)b * BW_H * BW_W * BW_C;
    const size_t base_b = (size_t)b * BW_H * BW_W;

    const size_t i0 = base_b + (size_t)y0 * BW_W + x;
    const size_t i1 = base_b + (size_t)y1 * BW_W + x;

    // coalesced 8B flow loads; NT (read-once stream, keep L2 for image)
    const floatx2* __restrict__ fl = (const floatx2*)flow;
    const floatx2 f0 = __builtin_nontemporal_load(fl + i0);
    const floatx2 f1 = __builtin_nontemporal_load(fl + i1);

    warp_one(imgb, f0, x, y0, out + i0 * BW_C);
    warp_one(imgb, f1, x, y1, out + i1 * BW_C);
}

extern "C" void kernel_launch(void* const* d_in, const int* in_sizes, int n_in,
                              void* d_out, int out_size, void* d_ws, size_t ws_size,
                              hipStream_t stream) {
    const float* image = (const float*)d_in[0];
    const float* flow  = (const float*)d_in[1];
    float* out = (float*)d_out;

    dim3 block(TILE_W, TILE_H / 2, 1);          // 64 x 4 = 256
    dim3 grid(NXCD * WG_PER_XCD, 1, 1);         // 28800, 1D for swizzle
    backwarp_kernel<<<grid, block, 0, stream>>>(image, flow, out);
}